// Round 1
// baseline (1014.839 us; speedup 1.0000x reference)
//
#include <hip/hip_runtime.h>
#include <math.h>

#define BB 2
#define SS 1024
#define DM 1024
#define DI 2048
#define DSTATE 16
#define DTR 64
#define NX 96          // DTR + 2*DSTATE
#define ROWS (BB*SS)   // 2048

// ---------------- LayerNorm: one block per row ----------------
__global__ __launch_bounds__(256) void ln_kernel(const float* __restrict__ x,
                                                 const float* __restrict__ gamma,
                                                 const float* __restrict__ beta,
                                                 float* __restrict__ h) {
    int row = blockIdx.x;
    const float* xr = x + (size_t)row * DM;
    float v[4];
    float s = 0.f;
#pragma unroll
    for (int i = 0; i < 4; i++) { v[i] = xr[threadIdx.x + i * 256]; s += v[i]; }
    __shared__ float red[4], red2[4];
    int lane = threadIdx.x & 63, wid = threadIdx.x >> 6;
#pragma unroll
    for (int m = 1; m < 64; m <<= 1) s += __shfl_xor(s, m);
    if (lane == 0) red[wid] = s;
    __syncthreads();
    float mean = (red[0] + red[1] + red[2] + red[3]) * (1.0f / DM);
    float vs = 0.f;
#pragma unroll
    for (int i = 0; i < 4; i++) { float dv = v[i] - mean; vs += dv * dv; }
#pragma unroll
    for (int m = 1; m < 64; m <<= 1) vs += __shfl_xor(vs, m);
    if (lane == 0) red2[wid] = vs;
    __syncthreads();
    float var = (red2[0] + red2[1] + red2[2] + red2[3]) * (1.0f / DM);
    float inv = rsqrtf(var + 1e-5f);
    float* hr = h + (size_t)row * DM;
#pragma unroll
    for (int i = 0; i < 4; i++) {
        int idx = threadIdx.x + i * 256;
        hr[idx] = (v[i] - mean) * inv * gamma[idx] + beta[idx];
    }
}

// ---------------- Generic fp32 tiled GEMM: C = A@B (+resid) ----------------
// A: MxK row-major, B: KxN row-major. BM=BN=64, BK=16, 256 threads, 4x4/thread.
__global__ __launch_bounds__(256) void gemm_nn(const float* __restrict__ A,
                                               const float* __restrict__ Bm,
                                               const float* __restrict__ resid,
                                               float* __restrict__ C,
                                               int M, int N, int K) {
    __shared__ float As[16][68];
    __shared__ float Bs[16][68];
    int t = threadIdx.x;
    int m0 = blockIdx.y * 64, n0 = blockIdx.x * 64;
    int ar = t >> 2;          // 0..63 tile row (A)
    int ac = (t & 3) * 4;     // k offset (A)
    int br = t >> 4;          // 0..15 k row (B)
    int bc = (t & 15) * 4;    // n offset (B)
    int tm = (t >> 4) * 4, tn = (t & 15) * 4;
    float acc[4][4] = {};
    for (int k0 = 0; k0 < K; k0 += 16) {
        float4 av = *(const float4*)(A + (size_t)(m0 + ar) * K + k0 + ac);
        float4 bv = *(const float4*)(Bm + (size_t)(k0 + br) * N + n0 + bc);
        As[ac + 0][ar] = av.x; As[ac + 1][ar] = av.y;
        As[ac + 2][ar] = av.z; As[ac + 3][ar] = av.w;
        *(float4*)&Bs[br][bc] = bv;
        __syncthreads();
#pragma unroll
        for (int kk = 0; kk < 16; kk++) {
            float a[4], b[4];
#pragma unroll
            for (int i = 0; i < 4; i++) { a[i] = As[kk][tm + i]; b[i] = Bs[kk][tn + i]; }
#pragma unroll
            for (int i = 0; i < 4; i++)
#pragma unroll
                for (int j = 0; j < 4; j++) acc[i][j] += a[i] * b[j];
        }
        __syncthreads();
    }
#pragma unroll
    for (int i = 0; i < 4; i++) {
        size_t ro = (size_t)(m0 + tm + i) * N + n0 + tn;
#pragma unroll
        for (int j = 0; j < 4; j++) {
            float r = resid ? resid[ro + j] : 0.f;
            C[ro + j] = acc[i][j] + r;
        }
    }
}

// ---------------- causal depthwise conv (width 4) + bias + silu ----------------
__global__ __launch_bounds__(256) void conv_silu(const float* __restrict__ xz,
                                                 const float* __restrict__ Wc,
                                                 const float* __restrict__ bc,
                                                 float* __restrict__ u) {
    int idx = blockIdx.x * 256 + threadIdx.x;   // over ROWS*DI
    int d = idx & (DI - 1);
    int row = idx >> 11;          // b*SS + t
    int tpos = row & (SS - 1);
    float acc = bc[d];
#pragma unroll
    for (int k = 0; k < 4; k++) {
        int tt = tpos - 3 + k;
        if (tt >= 0) acc += xz[(size_t)(row - 3 + k) * (2 * DI) + d] * Wc[d * 4 + k];
    }
    u[idx] = acc / (1.f + __expf(-acc));   // silu
}

// ---------------- x_dbl = u @ W_x (K=2048, N=96), one row per block ----------------
__global__ __launch_bounds__(128) void xdbl_kernel(const float* __restrict__ u,
                                                   const float* __restrict__ W_x,
                                                   float* __restrict__ xdbl) {
    int row = blockIdx.x;
    __shared__ float us[DI];
    for (int k = threadIdx.x; k < DI; k += 128) us[k] = u[(size_t)row * DI + k];
    __syncthreads();
    int col = threadIdx.x;
    if (col < NX) {
        float acc = 0.f;
        for (int k = 0; k < DI; k++) acc += us[k] * W_x[(size_t)k * NX + col];
        xdbl[(size_t)row * NX + col] = acc;
    }
}

// ---------------- dt = softplus(dt_r @ W_dt + b_dt) ----------------
__global__ __launch_bounds__(256) void dt_kernel(const float* __restrict__ xdbl,
                                                 const float* __restrict__ W_dt,
                                                 const float* __restrict__ b_dt,
                                                 float* __restrict__ dt) {
    int row = blockIdx.y;
    int d = blockIdx.x * 256 + threadIdx.x;
    __shared__ float dr[DTR];
    if (threadIdx.x < DTR) dr[threadIdx.x] = xdbl[(size_t)row * NX + threadIdx.x];
    __syncthreads();
    float acc = b_dt[d];
#pragma unroll 8
    for (int j = 0; j < DTR; j++) acc += dr[j] * W_dt[(size_t)j * DI + d];
    float sp = (acc > 20.f) ? acc : log1pf(expf(acc));
    dt[(size_t)row * DI + d] = sp;
}

// ---------------- selective scan: 16 lanes per (b,d) channel ----------------
__global__ __launch_bounds__(256) void scan_kernel(const float* __restrict__ dt,
                                                   const float* __restrict__ u,
                                                   const float* __restrict__ xdbl,
                                                   const float* __restrict__ A_log,
                                                   float* __restrict__ y) {
    int c = blockIdx.x * 16 + (threadIdx.x >> 4);  // channel 0..4095
    int n = threadIdx.x & 15;
    int b = c >> 11;          // c / DI
    int d = c & (DI - 1);
    float Av = -__expf(A_log[d * DSTATE + n] * 1.0f);
    // use accurate exp for A (weights): expf
    Av = -expf(A_log[d * DSTATE + n]);
    float h = 0.f;
    const size_t base = (size_t)b * SS;
    for (int t = 0; t < SS; t++) {
        size_t r = base + t;
        float dtv = dt[r * DI + d];
        float uv = u[r * DI + d];
        float Bv = xdbl[r * NX + DTR + n];
        float Cv = xdbl[r * NX + DTR + DSTATE + n];
        h = __expf(dtv * Av) * h + dtv * uv * Bv;
        float p = h * Cv;
        p += __shfl_xor(p, 1);
        p += __shfl_xor(p, 2);
        p += __shfl_xor(p, 4);
        p += __shfl_xor(p, 8);
        if (n == 0) y[r * DI + d] = p;
    }
}

// ---------------- y2 = (y + u*Dskip) * silu(z) ----------------
__global__ __launch_bounds__(256) void ewise_kernel(const float* __restrict__ y,
                                                    const float* __restrict__ u,
                                                    const float* __restrict__ xz,
                                                    const float* __restrict__ Dskip,
                                                    float* __restrict__ y2) {
    int idx = blockIdx.x * 256 + threadIdx.x;   // ROWS*DI
    int d = idx & (DI - 1);
    int row = idx >> 11;
    float z = xz[(size_t)row * (2 * DI) + DI + d];
    float sz = z / (1.f + __expf(-z));
    y2[idx] = (y[idx] + u[idx] * Dskip[d]) * sz;
}

extern "C" void kernel_launch(void* const* d_in, const int* in_sizes, int n_in,
                              void* d_out, int out_size, void* d_ws, size_t ws_size,
                              hipStream_t stream) {
    const float* x      = (const float*)d_in[0];
    const float* gamma  = (const float*)d_in[1];
    const float* beta   = (const float*)d_in[2];
    const float* W_in   = (const float*)d_in[3];
    const float* W_conv = (const float*)d_in[4];
    const float* b_conv = (const float*)d_in[5];
    const float* W_x    = (const float*)d_in[6];
    const float* W_dt   = (const float*)d_in[7];
    const float* b_dt   = (const float*)d_in[8];
    const float* A_log  = (const float*)d_in[9];
    const float* Dskip  = (const float*)d_in[10];
    const float* W_out  = (const float*)d_in[11];
    float* out = (float*)d_out;

    float* ws   = (float*)d_ws;
    float* xz   = ws;                              // ROWS*2*DI = 8,388,608
    float* u    = xz + (size_t)ROWS * 2 * DI;      // ROWS*DI   = 4,194,304
    float* xdbl = u + (size_t)ROWS * DI;           // ROWS*NX   = 196,608
    float* dt   = xdbl + (size_t)ROWS * NX;        // ROWS*DI
    float* y    = dt + (size_t)ROWS * DI;          // ROWS*DI
    float* h    = y;  // h (LN out) is dead before y is written — reuse

    // 1. LayerNorm
    ln_kernel<<<ROWS, 256, 0, stream>>>(x, gamma, beta, h);
    // 2. xz = h @ W_in   (2048x1024 @ 1024x4096)
    gemm_nn<<<dim3(2 * DI / 64, ROWS / 64), 256, 0, stream>>>(h, W_in, nullptr, xz,
                                                              ROWS, 2 * DI, DM);
    // 3. u = silu(causal depthwise conv(xi) + b_conv)
    conv_silu<<<ROWS * DI / 256, 256, 0, stream>>>(xz, W_conv, b_conv, u);
    // 4. x_dbl = u @ W_x  (2048x2048 @ 2048x96)
    xdbl_kernel<<<ROWS, 128, 0, stream>>>(u, W_x, xdbl);
    // 5. dt = softplus(dt_r @ W_dt + b_dt)
    dt_kernel<<<dim3(DI / 256, ROWS), 256, 0, stream>>>(xdbl, W_dt, b_dt, dt);
    // 6. selective scan -> y
    scan_kernel<<<(BB * DI) / 16, 256, 0, stream>>>(dt, u, xdbl, A_log, y);
    // 7. y = (y + u*Dskip) * silu(z)   (in-place)
    ewise_kernel<<<ROWS * DI / 256, 256, 0, stream>>>(y, u, xz, Dskip, y);
    // 8. out = x + y @ W_out  (2048x2048 @ 2048x1024)
    gemm_nn<<<dim3(DM / 64, ROWS / 64), 256, 0, stream>>>(y, W_out, x, out,
                                                          ROWS, DM, DI);
}

// Round 2
// 704.493 us; speedup vs baseline: 1.4405x; 1.4405x over previous
//
#include <hip/hip_runtime.h>
#include <math.h>

#define BB 2
#define SS 1024
#define DM 1024
#define DI 2048
#define DSTATE 16
#define DTR 64
#define NX 96          // DTR + 2*DSTATE
#define ROWS (BB*SS)   // 2048
#define NCHUNK 16
#define LC (SS/NCHUNK) // 64
#define NCH (BB*DI)    // 4096 channels

// ---------------- LayerNorm: one block per row ----------------
__global__ __launch_bounds__(256) void ln_kernel(const float* __restrict__ x,
                                                 const float* __restrict__ gamma,
                                                 const float* __restrict__ beta,
                                                 float* __restrict__ h) {
    int row = blockIdx.x;
    const float* xr = x + (size_t)row * DM;
    float v[4];
    float s = 0.f;
#pragma unroll
    for (int i = 0; i < 4; i++) { v[i] = xr[threadIdx.x + i * 256]; s += v[i]; }
    __shared__ float red[4], red2[4];
    int lane = threadIdx.x & 63, wid = threadIdx.x >> 6;
#pragma unroll
    for (int m = 1; m < 64; m <<= 1) s += __shfl_xor(s, m);
    if (lane == 0) red[wid] = s;
    __syncthreads();
    float mean = (red[0] + red[1] + red[2] + red[3]) * (1.0f / DM);
    float vs = 0.f;
#pragma unroll
    for (int i = 0; i < 4; i++) { float dv = v[i] - mean; vs += dv * dv; }
#pragma unroll
    for (int m = 1; m < 64; m <<= 1) vs += __shfl_xor(vs, m);
    if (lane == 0) red2[wid] = vs;
    __syncthreads();
    float var = (red2[0] + red2[1] + red2[2] + red2[3]) * (1.0f / DM);
    float inv = rsqrtf(var + 1e-5f);
    float* hr = h + (size_t)row * DM;
#pragma unroll
    for (int i = 0; i < 4; i++) {
        int idx = threadIdx.x + i * 256;
        hr[idx] = (v[i] - mean) * inv * gamma[idx] + beta[idx];
    }
}

// ---------------- Generic fp32 tiled GEMM: C = A@B (+resid) ----------------
__global__ __launch_bounds__(256) void gemm_nn(const float* __restrict__ A,
                                               const float* __restrict__ Bm,
                                               const float* __restrict__ resid,
                                               float* __restrict__ C,
                                               int M, int N, int K) {
    __shared__ float As[16][68];
    __shared__ float Bs[16][68];
    int t = threadIdx.x;
    int m0 = blockIdx.y * 64, n0 = blockIdx.x * 64;
    int ar = t >> 2;
    int ac = (t & 3) * 4;
    int br = t >> 4;
    int bc = (t & 15) * 4;
    int tm = (t >> 4) * 4, tn = (t & 15) * 4;
    float acc[4][4] = {};
    for (int k0 = 0; k0 < K; k0 += 16) {
        float4 av = *(const float4*)(A + (size_t)(m0 + ar) * K + k0 + ac);
        float4 bv = *(const float4*)(Bm + (size_t)(k0 + br) * N + n0 + bc);
        As[ac + 0][ar] = av.x; As[ac + 1][ar] = av.y;
        As[ac + 2][ar] = av.z; As[ac + 3][ar] = av.w;
        *(float4*)&Bs[br][bc] = bv;
        __syncthreads();
#pragma unroll
        for (int kk = 0; kk < 16; kk++) {
            float a[4], b[4];
#pragma unroll
            for (int i = 0; i < 4; i++) { a[i] = As[kk][tm + i]; b[i] = Bs[kk][tn + i]; }
#pragma unroll
            for (int i = 0; i < 4; i++)
#pragma unroll
                for (int j = 0; j < 4; j++) acc[i][j] += a[i] * b[j];
        }
        __syncthreads();
    }
#pragma unroll
    for (int i = 0; i < 4; i++) {
        size_t ro = (size_t)(m0 + tm + i) * N + n0 + tn;
#pragma unroll
        for (int j = 0; j < 4; j++) {
            float r = resid ? resid[ro + j] : 0.f;
            C[ro + j] = acc[i][j] + r;
        }
    }
}

// ---------------- causal depthwise conv (width 4) + bias + silu ----------------
__global__ __launch_bounds__(256) void conv_silu(const float* __restrict__ xz,
                                                 const float* __restrict__ Wc,
                                                 const float* __restrict__ bc,
                                                 float* __restrict__ u) {
    int idx = blockIdx.x * 256 + threadIdx.x;
    int d = idx & (DI - 1);
    int row = idx >> 11;
    int tpos = row & (SS - 1);
    float acc = bc[d];
#pragma unroll
    for (int k = 0; k < 4; k++) {
        int tt = tpos - 3 + k;
        if (tt >= 0) acc += xz[(size_t)(row - 3 + k) * (2 * DI) + d] * Wc[d * 4 + k];
    }
    u[idx] = acc / (1.f + __expf(-acc));
}

// ---------------- x_dbl = u @ W_x (K=2048, N=96) ----------------
__global__ __launch_bounds__(128) void xdbl_kernel(const float* __restrict__ u,
                                                   const float* __restrict__ W_x,
                                                   float* __restrict__ xdbl) {
    int row = blockIdx.x;
    __shared__ float us[DI];
    for (int k = threadIdx.x; k < DI; k += 128) us[k] = u[(size_t)row * DI + k];
    __syncthreads();
    int col = threadIdx.x;
    if (col < NX) {
        float acc = 0.f;
        for (int k = 0; k < DI; k++) acc += us[k] * W_x[(size_t)k * NX + col];
        xdbl[(size_t)row * NX + col] = acc;
    }
}

// ---------------- dt = softplus(dt_r @ W_dt + b_dt) ----------------
__global__ __launch_bounds__(256) void dt_kernel(const float* __restrict__ xdbl,
                                                 const float* __restrict__ W_dt,
                                                 const float* __restrict__ b_dt,
                                                 float* __restrict__ dt) {
    int row = blockIdx.y;
    int d = blockIdx.x * 256 + threadIdx.x;
    __shared__ float dr[DTR];
    if (threadIdx.x < DTR) dr[threadIdx.x] = xdbl[(size_t)row * NX + threadIdx.x];
    __syncthreads();
    float acc = b_dt[d];
#pragma unroll 8
    for (int j = 0; j < DTR; j++) acc += dr[j] * W_dt[(size_t)j * DI + d];
    float sp = (acc > 20.f) ? acc : log1pf(expf(acc));
    dt[(size_t)row * DI + d] = sp;
}

// ---------------- chunked scan pass A: local scans + chunk dA-products ----------------
// grid: (NCH/16, NCHUNK), block 256 = 16 channels x 16 states
__global__ __launch_bounds__(256) void scan_chunk1(const float* __restrict__ dt,
                                                   const float* __restrict__ u,
                                                   const float* __restrict__ xdbl,
                                                   const float* __restrict__ A_log,
                                                   float* __restrict__ Aprod,
                                                   float* __restrict__ hloc) {
    int c = blockIdx.x * 16 + (threadIdx.x >> 4);
    int n = threadIdx.x & 15;
    int j = blockIdx.y;
    int b = c >> 11;
    int d = c & (DI - 1);
    float Av = -expf(A_log[d * DSTATE + n]);
    float h = 0.f, P = 1.f;
    size_t r0 = (size_t)b * SS + (size_t)j * LC;
    for (int t = 0; t < LC; t++) {
        size_t r = r0 + t;
        float dtv = dt[r * DI + d];
        float uv = u[r * DI + d];
        float Bv = xdbl[r * NX + DTR + n];
        float dA = __expf(dtv * Av);
        P *= dA;
        h = dA * h + dtv * uv * Bv;
    }
    size_t o = (size_t)j * (NCH * DSTATE) + (size_t)c * DSTATE + n;
    Aprod[o] = P;
    hloc[o] = h;
}

// ---------------- chunked scan pass B: sequential combine over chunks ----------------
__global__ __launch_bounds__(256) void scan_combine(const float* __restrict__ Aprod,
                                                    const float* __restrict__ hloc,
                                                    float* __restrict__ h0arr) {
    int idx = blockIdx.x * 256 + threadIdx.x;   // over NCH*DSTATE = 65536
    float h = 0.f;
#pragma unroll
    for (int j = 0; j < NCHUNK; j++) {
        size_t o = (size_t)j * (NCH * DSTATE) + idx;
        h0arr[o] = h;
        h = Aprod[o] * h + hloc[o];
    }
}

// ---------------- chunked scan pass C: seeded local scan + y + fused ewise ----------------
// y2 = (C.h + u*Dskip) * silu(z)
__global__ __launch_bounds__(256) void scan_chunk2(const float* __restrict__ dt,
                                                   const float* __restrict__ u,
                                                   const float* __restrict__ xdbl,
                                                   const float* __restrict__ A_log,
                                                   const float* __restrict__ h0arr,
                                                   const float* __restrict__ xz,
                                                   const float* __restrict__ Dskip,
                                                   float* __restrict__ y2) {
    int c = blockIdx.x * 16 + (threadIdx.x >> 4);
    int n = threadIdx.x & 15;
    int j = blockIdx.y;
    int b = c >> 11;
    int d = c & (DI - 1);
    float Av = -expf(A_log[d * DSTATE + n]);
    float h = h0arr[(size_t)j * (NCH * DSTATE) + (size_t)c * DSTATE + n];
    float Dv = Dskip[d];
    size_t r0 = (size_t)b * SS + (size_t)j * LC;
    for (int t = 0; t < LC; t++) {
        size_t r = r0 + t;
        float dtv = dt[r * DI + d];
        float uv = u[r * DI + d];
        float Bv = xdbl[r * NX + DTR + n];
        float Cv = xdbl[r * NX + DTR + DSTATE + n];
        float dA = __expf(dtv * Av);
        h = dA * h + dtv * uv * Bv;
        float p = h * Cv;
        p += __shfl_xor(p, 1);
        p += __shfl_xor(p, 2);
        p += __shfl_xor(p, 4);
        p += __shfl_xor(p, 8);
        if (n == 0) {
            float zz = xz[r * (2 * DI) + DI + d];
            float sz = zz / (1.f + __expf(-zz));
            y2[r * DI + d] = (p + uv * Dv) * sz;
        }
    }
}

extern "C" void kernel_launch(void* const* d_in, const int* in_sizes, int n_in,
                              void* d_out, int out_size, void* d_ws, size_t ws_size,
                              hipStream_t stream) {
    const float* x      = (const float*)d_in[0];
    const float* gamma  = (const float*)d_in[1];
    const float* beta   = (const float*)d_in[2];
    const float* W_in   = (const float*)d_in[3];
    const float* W_conv = (const float*)d_in[4];
    const float* b_conv = (const float*)d_in[5];
    const float* W_x    = (const float*)d_in[6];
    const float* W_dt   = (const float*)d_in[7];
    const float* b_dt   = (const float*)d_in[8];
    const float* A_log  = (const float*)d_in[9];
    const float* Dskip  = (const float*)d_in[10];
    const float* W_out  = (const float*)d_in[11];
    float* out = (float*)d_out;

    float* ws    = (float*)d_ws;
    float* xz    = ws;                               // ROWS*2*DI = 8,388,608 f
    float* u     = xz + (size_t)ROWS * 2 * DI;       // ROWS*DI
    float* xdbl  = u + (size_t)ROWS * DI;            // ROWS*NX
    float* dt    = xdbl + (size_t)ROWS * NX;         // ROWS*DI
    float* y     = dt + (size_t)ROWS * DI;           // ROWS*DI (aliases h)
    float* Aprod = y + (size_t)ROWS * DI;            // NCHUNK*NCH*DSTATE = 1M f
    float* hloc  = Aprod + (size_t)NCHUNK * NCH * DSTATE;
    float* h0arr = hloc + (size_t)NCHUNK * NCH * DSTATE;
    float* h     = y;   // LN output; dead before y2 is written

    // 1. LayerNorm
    ln_kernel<<<ROWS, 256, 0, stream>>>(x, gamma, beta, h);
    // 2. xz = h @ W_in
    gemm_nn<<<dim3(2 * DI / 64, ROWS / 64), 256, 0, stream>>>(h, W_in, nullptr, xz,
                                                              ROWS, 2 * DI, DM);
    // 3. u = silu(conv(xi) + b_conv)
    conv_silu<<<ROWS * DI / 256, 256, 0, stream>>>(xz, W_conv, b_conv, u);
    // 4. x_dbl = u @ W_x
    xdbl_kernel<<<ROWS, 128, 0, stream>>>(u, W_x, xdbl);
    // 5. dt = softplus(dt_r @ W_dt + b_dt)
    dt_kernel<<<dim3(DI / 256, ROWS), 256, 0, stream>>>(xdbl, W_dt, b_dt, dt);
    // 6. chunked selective scan (3 passes) + fused (y+u*D)*silu(z)
    scan_chunk1<<<dim3(NCH / 16, NCHUNK), 256, 0, stream>>>(dt, u, xdbl, A_log, Aprod, hloc);
    scan_combine<<<(NCH * DSTATE) / 256, 256, 0, stream>>>(Aprod, hloc, h0arr);
    scan_chunk2<<<dim3(NCH / 16, NCHUNK), 256, 0, stream>>>(dt, u, xdbl, A_log, h0arr,
                                                            xz, Dskip, y);
    // 7. out = x + y @ W_out
    gemm_nn<<<dim3(DM / 64, ROWS / 64), 256, 0, stream>>>(y, W_out, x, out,
                                                          ROWS, DM, DI);
}

// Round 3
// 454.754 us; speedup vs baseline: 2.2316x; 1.5492x over previous
//
#include <hip/hip_runtime.h>
#include <math.h>

#define BB 2
#define SS 1024
#define DM 1024
#define DI 2048
#define DSTATE 16
#define DTR 64
#define NX 96          // DTR + 2*DSTATE
#define ROWS (BB*SS)   // 2048
#define NCHUNK 16
#define LC (SS/NCHUNK) // 64
#define NCH (BB*DI)    // 4096 channels

typedef __bf16 bf16x8 __attribute__((ext_vector_type(8)));
typedef float f32x4 __attribute__((ext_vector_type(4)));

static __device__ __forceinline__ unsigned short f2bf(float f) {
    unsigned u = __builtin_bit_cast(unsigned, f);
    unsigned r = (u + 0x7fff + ((u >> 16) & 1)) >> 16;
    return (unsigned short)r;
}

// ---------------- LayerNorm -> bf16 ----------------
__global__ __launch_bounds__(256) void ln_kernel(const float* __restrict__ x,
                                                 const float* __restrict__ gamma,
                                                 const float* __restrict__ beta,
                                                 unsigned short* __restrict__ h) {
    int row = blockIdx.x;
    const float* xr = x + (size_t)row * DM;
    float v[4];
    float s = 0.f;
#pragma unroll
    for (int i = 0; i < 4; i++) { v[i] = xr[threadIdx.x + i * 256]; s += v[i]; }
    __shared__ float red[4], red2[4];
    int lane = threadIdx.x & 63, wid = threadIdx.x >> 6;
#pragma unroll
    for (int m = 1; m < 64; m <<= 1) s += __shfl_xor(s, m);
    if (lane == 0) red[wid] = s;
    __syncthreads();
    float mean = (red[0] + red[1] + red[2] + red[3]) * (1.0f / DM);
    float vs = 0.f;
#pragma unroll
    for (int i = 0; i < 4; i++) { float dv = v[i] - mean; vs += dv * dv; }
#pragma unroll
    for (int m = 1; m < 64; m <<= 1) vs += __shfl_xor(vs, m);
    if (lane == 0) red2[wid] = vs;
    __syncthreads();
    float var = (red2[0] + red2[1] + red2[2] + red2[3]) * (1.0f / DM);
    float inv = rsqrtf(var + 1e-5f);
    unsigned short* hr = h + (size_t)row * DM;
#pragma unroll
    for (int i = 0; i < 4; i++) {
        int idx = threadIdx.x + i * 256;
        hr[idx] = f2bf((v[i] - mean) * inv * gamma[idx] + beta[idx]);
    }
}

// ---------------- fp32 (KxN) -> bf16 transposed (NxK) ----------------
__global__ __launch_bounds__(256) void transpose_bf16(const float* __restrict__ W,
                                                      unsigned short* __restrict__ WT,
                                                      int K, int N) {
    __shared__ unsigned short tile[32][33];
    int n0 = blockIdx.x * 32, k0 = blockIdx.y * 32;
    int tx = threadIdx.x & 31, ty = threadIdx.x >> 5;   // ty 0..7
#pragma unroll
    for (int r = 0; r < 4; r++)
        tile[ty + r * 8][tx] = f2bf(W[(size_t)(k0 + ty + r * 8) * N + n0 + tx]);
    __syncthreads();
#pragma unroll
    for (int r = 0; r < 4; r++)
        WT[(size_t)(n0 + ty + r * 8) * K + k0 + tx] = tile[tx][ty + r * 8];
}

// ---------------- bf16 MFMA GEMM: C(f32) = A(bf16,MxK) @ BT(bf16,NxK)^T (+resid) ----------------
// 128x128 tile, 256 thr = 4 waves (2x2), each wave 64x64 via 4x4 mfma_16x16x32.
__global__ __launch_bounds__(256) void gemm_mfma(const __bf16* __restrict__ A,
                                                 const __bf16* __restrict__ BT,
                                                 const float* __restrict__ resid,
                                                 float* __restrict__ C,
                                                 int M, int N, int K) {
    __shared__ __bf16 As[128 * 32];
    __shared__ __bf16 Bs[128 * 32];
    int tid = threadIdx.x;
    int w = tid >> 6, lane = tid & 63;
    int wr = w >> 1, wc = w & 1;
    int m0 = blockIdx.y * 128, n0 = blockIdx.x * 128;

    f32x4 acc[4][4] = {};

    int srow = lane >> 2;      // 0..15
    int sgran = lane & 3;      // 16B granule within 64B row
    const __bf16* gA = A + (size_t)(m0 + w * 32) * K;
    const __bf16* gB = BT + (size_t)(n0 + w * 32) * K;
    int fr = lane & 15, q = lane >> 4;

    for (int k0 = 0; k0 < K; k0 += 32) {
        __syncthreads();
#pragma unroll
        for (int c = 0; c < 2; c++) {
            const __bf16* ga = gA + (size_t)(c * 16 + srow) * K + k0 + sgran * 8;
            const __bf16* gb = gB + (size_t)(c * 16 + srow) * K + k0 + sgran * 8;
            __builtin_amdgcn_global_load_lds(
                (const __attribute__((address_space(1))) void*)ga,
                (__attribute__((address_space(3))) void*)&As[(w * 32 + c * 16) * 32], 16, 0, 0);
            __builtin_amdgcn_global_load_lds(
                (const __attribute__((address_space(1))) void*)gb,
                (__attribute__((address_space(3))) void*)&Bs[(w * 32 + c * 16) * 32], 16, 0, 0);
        }
        __syncthreads();
        bf16x8 af[4], bfr[4];
#pragma unroll
        for (int i = 0; i < 4; i++)
            af[i] = *(const bf16x8*)&As[(wr * 64 + i * 16 + fr) * 32 + q * 8];
#pragma unroll
        for (int j = 0; j < 4; j++)
            bfr[j] = *(const bf16x8*)&Bs[(wc * 64 + j * 16 + fr) * 32 + q * 8];
#pragma unroll
        for (int i = 0; i < 4; i++)
#pragma unroll
            for (int j = 0; j < 4; j++)
                acc[i][j] = __builtin_amdgcn_mfma_f32_16x16x32_bf16(af[i], bfr[j], acc[i][j], 0, 0, 0);
    }
    // epilogue: row = quad*4+r, col = lane&15  [measured m89/m91 layout]
#pragma unroll
    for (int i = 0; i < 4; i++) {
#pragma unroll
        for (int j = 0; j < 4; j++) {
#pragma unroll
            for (int r = 0; r < 4; r++) {
                size_t ro = (size_t)(m0 + wr * 64 + i * 16 + q * 4 + r) * N
                          + n0 + wc * 64 + j * 16 + fr;
                float v = acc[i][j][r];
                if (resid) v += resid[ro];
                C[ro] = v;
            }
        }
    }
}

// ---------------- causal depthwise conv (width 4) + bias + silu ----------------
__global__ __launch_bounds__(256) void conv_silu(const float* __restrict__ xz,
                                                 const float* __restrict__ Wc,
                                                 const float* __restrict__ bc,
                                                 float* __restrict__ u) {
    int idx = blockIdx.x * 256 + threadIdx.x;
    int d = idx & (DI - 1);
    int row = idx >> 11;
    int tpos = row & (SS - 1);
    float acc = bc[d];
#pragma unroll
    for (int k = 0; k < 4; k++) {
        int tt = tpos - 3 + k;
        if (tt >= 0) acc += xz[(size_t)(row - 3 + k) * (2 * DI) + d] * Wc[d * 4 + k];
    }
    u[idx] = acc / (1.f + __expf(-acc));
}

// ---------------- x_dbl = u @ W_x (K=2048, N=96) ----------------
__global__ __launch_bounds__(128) void xdbl_kernel(const float* __restrict__ u,
                                                   const float* __restrict__ W_x,
                                                   float* __restrict__ xdbl) {
    int row = blockIdx.x;
    __shared__ float us[DI];
    for (int k = threadIdx.x; k < DI; k += 128) us[k] = u[(size_t)row * DI + k];
    __syncthreads();
    int col = threadIdx.x;
    if (col < NX) {
        float acc = 0.f;
        for (int k = 0; k < DI; k++) acc += us[k] * W_x[(size_t)k * NX + col];
        xdbl[(size_t)row * NX + col] = acc;
    }
}

// ---------------- dt = softplus(dt_r @ W_dt + b_dt) ----------------
__global__ __launch_bounds__(256) void dt_kernel(const float* __restrict__ xdbl,
                                                 const float* __restrict__ W_dt,
                                                 const float* __restrict__ b_dt,
                                                 float* __restrict__ dt) {
    int row = blockIdx.y;
    int d = blockIdx.x * 256 + threadIdx.x;
    __shared__ float dr[DTR];
    if (threadIdx.x < DTR) dr[threadIdx.x] = xdbl[(size_t)row * NX + threadIdx.x];
    __syncthreads();
    float acc = b_dt[d];
#pragma unroll 8
    for (int j = 0; j < DTR; j++) acc += dr[j] * W_dt[(size_t)j * DI + d];
    float sp = (acc > 20.f) ? acc : log1pf(expf(acc));
    dt[(size_t)row * DI + d] = sp;
}

// ---------------- chunked scan pass A ----------------
__global__ __launch_bounds__(256) void scan_chunk1(const float* __restrict__ dt,
                                                   const float* __restrict__ u,
                                                   const float* __restrict__ xdbl,
                                                   const float* __restrict__ A_log,
                                                   float* __restrict__ Aprod,
                                                   float* __restrict__ hloc) {
    int c = blockIdx.x * 16 + (threadIdx.x >> 4);
    int n = threadIdx.x & 15;
    int j = blockIdx.y;
    int b = c >> 11;
    int d = c & (DI - 1);
    float Av = -expf(A_log[d * DSTATE + n]);
    float h = 0.f, P = 1.f;
    size_t r0 = (size_t)b * SS + (size_t)j * LC;
    for (int t = 0; t < LC; t++) {
        size_t r = r0 + t;
        float dtv = dt[r * DI + d];
        float uv = u[r * DI + d];
        float Bv = xdbl[r * NX + DTR + n];
        float dA = __expf(dtv * Av);
        P *= dA;
        h = dA * h + dtv * uv * Bv;
    }
    size_t o = (size_t)j * (NCH * DSTATE) + (size_t)c * DSTATE + n;
    Aprod[o] = P;
    hloc[o] = h;
}

// ---------------- chunked scan pass B ----------------
__global__ __launch_bounds__(256) void scan_combine(const float* __restrict__ Aprod,
                                                    const float* __restrict__ hloc,
                                                    float* __restrict__ h0arr) {
    int idx = blockIdx.x * 256 + threadIdx.x;
    float h = 0.f;
#pragma unroll
    for (int j = 0; j < NCHUNK; j++) {
        size_t o = (size_t)j * (NCH * DSTATE) + idx;
        h0arr[o] = h;
        h = Aprod[o] * h + hloc[o];
    }
}

// ---------------- chunked scan pass C + fused gate, bf16 out ----------------
__global__ __launch_bounds__(256) void scan_chunk2(const float* __restrict__ dt,
                                                   const float* __restrict__ u,
                                                   const float* __restrict__ xdbl,
                                                   const float* __restrict__ A_log,
                                                   const float* __restrict__ h0arr,
                                                   const float* __restrict__ xz,
                                                   const float* __restrict__ Dskip,
                                                   unsigned short* __restrict__ y2) {
    int c = blockIdx.x * 16 + (threadIdx.x >> 4);
    int n = threadIdx.x & 15;
    int j = blockIdx.y;
    int b = c >> 11;
    int d = c & (DI - 1);
    float Av = -expf(A_log[d * DSTATE + n]);
    float h = h0arr[(size_t)j * (NCH * DSTATE) + (size_t)c * DSTATE + n];
    float Dv = Dskip[d];
    size_t r0 = (size_t)b * SS + (size_t)j * LC;
    for (int t = 0; t < LC; t++) {
        size_t r = r0 + t;
        float dtv = dt[r * DI + d];
        float uv = u[r * DI + d];
        float Bv = xdbl[r * NX + DTR + n];
        float Cv = xdbl[r * NX + DTR + DSTATE + n];
        float dA = __expf(dtv * Av);
        h = dA * h + dtv * uv * Bv;
        float p = h * Cv;
        p += __shfl_xor(p, 1);
        p += __shfl_xor(p, 2);
        p += __shfl_xor(p, 4);
        p += __shfl_xor(p, 8);
        if (n == 0) {
            float zz = xz[r * (2 * DI) + DI + d];
            float sz = zz / (1.f + __expf(-zz));
            y2[r * DI + d] = f2bf((p + uv * Dv) * sz);
        }
    }
}

extern "C" void kernel_launch(void* const* d_in, const int* in_sizes, int n_in,
                              void* d_out, int out_size, void* d_ws, size_t ws_size,
                              hipStream_t stream) {
    const float* x      = (const float*)d_in[0];
    const float* gamma  = (const float*)d_in[1];
    const float* beta   = (const float*)d_in[2];
    const float* W_in   = (const float*)d_in[3];
    const float* W_conv = (const float*)d_in[4];
    const float* b_conv = (const float*)d_in[5];
    const float* W_x    = (const float*)d_in[6];
    const float* W_dt   = (const float*)d_in[7];
    const float* b_dt   = (const float*)d_in[8];
    const float* A_log  = (const float*)d_in[9];
    const float* Dskip  = (const float*)d_in[10];
    const float* W_out  = (const float*)d_in[11];
    float* out = (float*)d_out;

    float* ws    = (float*)d_ws;
    float* xz    = ws;                               // 8,388,608 f
    float* u     = xz + (size_t)ROWS * 2 * DI;       // 4,194,304 f
    float* xdbl  = u + (size_t)ROWS * DI;            // 196,608 f
    float* dt    = xdbl + (size_t)ROWS * NX;         // 4,194,304 f
    float* Aprod = dt + (size_t)ROWS * DI;           // 1,048,576 f
    float* hloc  = Aprod + (size_t)NCHUNK * NCH * DSTATE;
    float* h0arr = hloc + (size_t)NCHUNK * NCH * DSTATE;
    unsigned short* h_bf   = (unsigned short*)(h0arr + (size_t)NCHUNK * NCH * DSTATE); // 2M us
    unsigned short* y_bf   = h_bf + (size_t)ROWS * DM;        // 4M us
    unsigned short* W_inT  = y_bf + (size_t)ROWS * DI;        // 4M us (4096x1024)
    unsigned short* W_outT = W_inT + (size_t)(2 * DI) * DM;   // 2M us (1024x2048)

    // weight transposes (bf16, N x K)
    transpose_bf16<<<dim3(2 * DI / 32, DM / 32), 256, 0, stream>>>(W_in, W_inT, DM, 2 * DI);
    transpose_bf16<<<dim3(DM / 32, DI / 32), 256, 0, stream>>>(W_out, W_outT, DI, DM);
    // 1. LayerNorm -> bf16
    ln_kernel<<<ROWS, 256, 0, stream>>>(x, gamma, beta, h_bf);
    // 2. xz = h @ W_in   (MFMA bf16)
    gemm_mfma<<<dim3(2 * DI / 128, ROWS / 128), 256, 0, stream>>>(
        (const __bf16*)h_bf, (const __bf16*)W_inT, nullptr, xz, ROWS, 2 * DI, DM);
    // 3. u = silu(conv(xi) + b_conv)
    conv_silu<<<ROWS * DI / 256, 256, 0, stream>>>(xz, W_conv, b_conv, u);
    // 4. x_dbl = u @ W_x
    xdbl_kernel<<<ROWS, 128, 0, stream>>>(u, W_x, xdbl);
    // 5. dt = softplus(dt_r @ W_dt + b_dt)
    dt_kernel<<<dim3(DI / 256, ROWS), 256, 0, stream>>>(xdbl, W_dt, b_dt, dt);
    // 6. chunked selective scan + fused gate -> y_bf
    scan_chunk1<<<dim3(NCH / 16, NCHUNK), 256, 0, stream>>>(dt, u, xdbl, A_log, Aprod, hloc);
    scan_combine<<<(NCH * DSTATE) / 256, 256, 0, stream>>>(Aprod, hloc, h0arr);
    scan_chunk2<<<dim3(NCH / 16, NCHUNK), 256, 0, stream>>>(dt, u, xdbl, A_log, h0arr,
                                                            xz, Dskip, y_bf);
    // 7. out = x + y @ W_out  (MFMA bf16)
    gemm_mfma<<<dim3(DM / 128, ROWS / 128), 256, 0, stream>>>(
        (const __bf16*)y_bf, (const __bf16*)W_outT, x, out, ROWS, DM, DI);
}